// Round 3
// baseline (73.488 us; speedup 1.0000x reference)
//
#include <hip/hip_runtime.h>
#include <math.h>

#define ROWS 1000000
#define NBLK 1024
#define NTHR 256
#define WAVES (NTHR / 64)            // 4 waves per block
#define GW (NBLK * WAVES)            // 4096 wave-groups total
#define ITER ((ROWS + GW * 8 - 1) / (GW * 8))   // 31
#define NBLK_B 977                    // ceil(250000 float4 / 256)
#define LN8 2.0794415416798357f

struct Params {
    const int*   x; const float* hidden; const int* pos;
    const float* loc_emb; const float* arr_emb; const float* dur_emb; const float* pos_emb;
    const float* f1rW1; const float* f1rb1; const float* f1rW2; const float* f1rb2;
    const float* f1W;   const float* f1b;
    const float* f2rW1; const float* f2rb1; const float* f2rW2; const float* f2rb2;
    const float* f2W;   const float* f2b;
    const float* f3rW1; const float* f3rb1; const float* f3rW2; const float* f3rb2;
    const float* f3W;   const float* f3b;
    const float* ln_g;  const float* ln_b;
    const float* ode_W; const float* ode_b;
    const float* oW1;   const float* ob1; const float* oW2; const float* ob2;
    const float* fc4_W; const float* fc4_b;
    const float* fc5_W; const float* fc5_b;
    const float* fc6_W; const float* fc6_b;
    const float* gWih;  const float* gbih; const float* gWhh; const float* gbhh;
    float* out; float* ws;
};

__device__ __forceinline__ float warmA(const float* ptr, int n4, int wt) {
    float a = 0.f;
    const float4* v = (const float4*)ptr;
    for (int i = wt; i < n4; i += 192) { float4 w = v[i]; a += w.x + w.y + w.z + w.w; }
    return a;
}

// ---------------------------------------------------------------------------
// K_A: redundant front (wave 0) + L2 warm (waves 1-3) + coalesced fc4 logits.
// Writes unnormalized logits to out[0:ROWS), (m, sumexp) partials to ws,
// and the three small outputs (from block 0).
// ---------------------------------------------------------------------------
__global__ __launch_bounds__(NTHR) void bigkernel(Params p)
{
    const int t   = threadIdx.x;
    const int bid = blockIdx.x;
    const int l   = t & 63;
    const int wid = t >> 6;
    const int wg  = bid * WAVES + wid;     // global wave id
    const float4* W4 = (const float4*)p.fc4_W;

    // ---- waves 1-3: warm L2 with front weights + own first fc4_W iters ----
    if (t >= 64) {
        const int wt = t - 64;
        float a0 = warmA(p.gWhh, 768, wt);
        a0 += warmA(p.gWih, 360, wt);
        a0 += warmA(p.oW1, 256, wt)   + warmA(p.oW2, 256, wt);
        a0 += warmA(p.fc5_W, 192, wt) + warmA(p.fc6_W, 192, wt);
        a0 += warmA(p.f1rW1, 128, wt) + warmA(p.f1rW2, 128, wt);
        a0 += warmA(p.f2rW1, 128, wt) + warmA(p.f2rW2, 128, wt);
        a0 += warmA(p.f3rW1, 128, wt) + warmA(p.f3rW2, 128, wt);
        a0 += warmA(p.ode_W, 40, wt);
        a0 += warmA(p.f1W, 20, wt) + warmA(p.f2W, 20, wt) + warmA(p.f3W, 20, wt);
        #pragma unroll
        for (int c = 0; c < 4; ++c) {
            float4 w = W4[(size_t)(c * GW + wg) * 64 + l];
            a0 += w.x + w.y + w.z + w.w;
        }
        asm volatile("" :: "v"(a0));   // keep warm loads alive
    }

    // ---- front-end, wave 0 only (identical to the round-1 passing code) ----
    __shared__ float e[3][16], tr[3][16], h1[3][16];
    __shared__ float praw[15], pnorm[15];
    __shared__ float ode0[32], odt[32], hvec[32], hnew[32], pe[32];
    __shared__ float gi[96], gh[96];
    __shared__ float a5[24], a6[24];
    __shared__ float red[4];

    if (t < 48) {
        int c = t >> 4, j = t & 15;
        const float* emb = (c == 0) ? (p.loc_emb + (size_t)p.x[0] * 16)
                         : (c == 1) ? (p.arr_emb + (size_t)p.x[1] * 16)
                                    : (p.dur_emb + (size_t)p.x[2] * 16);
        e[c][j] = emb[j];
    }
    if (t < 32) pe[t] = p.pos_emb[p.pos[0] * 32 + t];
    __syncthreads();

    for (int i = 0; i < 2; ++i) {
        if (t < 48) { int c = t >> 4, j = t & 15; tr[c][j] = fmaxf(e[c][j], 0.f); }
        __syncthreads();
        if (t < 48) {
            int c = t >> 4, j = t & 15;
            const float* W1 = ((c == 0) ? p.f1rW1 : (c == 1) ? p.f2rW1 : p.f3rW1) + i * 256 + j * 16;
            const float* b1 = ((c == 0) ? p.f1rb1 : (c == 1) ? p.f2rb1 : p.f3rb1) + i * 16;
            float a = b1[j];
            #pragma unroll
            for (int k = 0; k < 16; ++k) a += W1[k] * tr[c][k];
            h1[c][j] = fmaxf(a, 0.f);
        }
        __syncthreads();
        if (t < 48) {
            int c = t >> 4, j = t & 15;
            const float* W2 = ((c == 0) ? p.f1rW2 : (c == 1) ? p.f2rW2 : p.f3rW2) + i * 256 + j * 16;
            const float* b2 = ((c == 0) ? p.f1rb2 : (c == 1) ? p.f2rb2 : p.f3rb2) + i * 16;
            float a = b2[j];
            #pragma unroll
            for (int k = 0; k < 16; ++k) a += W2[k] * h1[c][k];
            e[c][j] += 0.3f * a;
        }
        __syncthreads();
    }

    if (t < 15) {
        int c = t / 5, q = t % 5;
        const float* W = ((c == 0) ? p.f1W : (c == 1) ? p.f2W : p.f3W) + q * 16;
        const float* b = ((c == 0) ? p.f1b : (c == 1) ? p.f2b : p.f3b);
        float a = b[q];
        #pragma unroll
        for (int k = 0; k < 16; ++k) a += W[k] * e[c][k];
        praw[t] = a;
    }
    __syncthreads();

    if (t == 0) {
        float mu = 0.f;
        for (int k = 0; k < 15; ++k) mu += praw[k];
        mu *= (1.f / 15.f);
        float var = 0.f;
        for (int k = 0; k < 15; ++k) { float d = praw[k] - mu; var += d * d; }
        var *= (1.f / 15.f);
        red[0] = mu;
        red[1] = rsqrtf(var + 1e-5f);
    }
    __syncthreads();
    if (t < 15) pnorm[t] = (praw[t] - red[0]) * red[1] * p.ln_g[t] + p.ln_b[t];
    if (t < 32) {
        float a = p.ode_b[t];
        const float* W = p.ode_W + t * 5;
        #pragma unroll
        for (int k = 0; k < 5; ++k) a += W[k] * praw[10 + k];
        ode0[t] = a;
    }
    __syncthreads();
    if (t < 32) {
        float a = p.ob1[t];
        const float* W = p.oW1 + t * 32;
        #pragma unroll
        for (int k = 0; k < 32; ++k) a += W[k] * fmaxf(ode0[k], 0.f);
        odt[t] = fmaxf(a, 0.f);
    }
    __syncthreads();
    if (t < 32) {
        float a = p.ob2[t];
        const float* W = p.oW2 + t * 32;
        #pragma unroll
        for (int k = 0; k < 32; ++k) a += W[k] * odt[k];
        hvec[t] = p.hidden[t] + ode0[t] + 0.3f * a;
    }
    __syncthreads();
    if (t < 64) {
        for (int q = t; q < 96; q += 64) {
            float a = p.gbih[q];
            const float* W = p.gWih + q * 15;
            #pragma unroll
            for (int k = 0; k < 15; ++k) a += W[k] * pnorm[k];
            gi[q] = a;
            float c2 = p.gbhh[q];
            const float* V = p.gWhh + q * 32;
            #pragma unroll
            for (int k = 0; k < 32; ++k) c2 += V[k] * hvec[k];
            gh[q] = c2;
        }
    }
    __syncthreads();
    if (t < 32) {
        float r = 1.f / (1.f + expf(-(gi[t] + gh[t])));
        float z = 1.f / (1.f + expf(-(gi[32 + t] + gh[32 + t])));
        float n = tanhf(gi[64 + t] + r * gh[64 + t]);
        float hn = (1.f - z) * n + z * hvec[t];
        hnew[t] = hn;
        if (bid == 0) p.out[ROWS + 48 + t] = hn;
    }
    __syncthreads();
    if (t < 24) {
        float a = p.fc5_b[t];
        const float* W = p.fc5_W + t * 32;
        #pragma unroll
        for (int k = 0; k < 32; ++k) a += W[k] * (hnew[k] + pe[k]);
        a5[t] = a;
        float b = p.fc6_b[t];
        const float* V = p.fc6_W + t * 32;
        #pragma unroll
        for (int k = 0; k < 32; ++k) b += V[k] * hnew[k];
        a6[t] = b;
    }
    __syncthreads();
    if (t == 0) {
        float m = -INFINITY;
        for (int k = 0; k < 24; ++k) m = fmaxf(m, a5[k]);
        float s = 0.f;
        for (int k = 0; k < 24; ++k) s += expf(a5[k] - m);
        red[2] = m + logf(s);
        m = -INFINITY;
        for (int k = 0; k < 24; ++k) m = fmaxf(m, a6[k]);
        s = 0.f;
        for (int k = 0; k < 24; ++k) s += expf(a6[k] - m);
        red[3] = m + logf(s);
    }
    __syncthreads();
    if (bid == 0 && t < 24) {
        p.out[ROWS + t]      = a5[t] - red[2];
        p.out[ROWS + 24 + t] = a6[t] - red[3];
    }

    // ---- fc4 logits: 8 lanes per row, fully coalesced ----
    float hr[32];
    #pragma unroll
    for (int k = 0; k < 32; ++k) hr[k] = hnew[k];

    const int j = l & 7;           // chunk index within row
    const int g = l >> 3;          // row within wave's group of 8
    float m = -INFINITY, s = 0.f;

    for (int c = 0; c < ITER; ++c) {
        const int rb = (c * GW + wg) * 8;     // wave-uniform row base
        const int my_row = rb + g;            // uniform within 8-lane group
        if (my_row < ROWS) {
            float4 w = W4[(size_t)rb * 8 + l];   // contiguous 1 KiB per wave
            float pp = w.x * hr[4*j] + w.y * hr[4*j+1]
                     + w.z * hr[4*j+2] + w.w * hr[4*j+3];
            pp += __shfl_xor(pp, 1);
            pp += __shfl_xor(pp, 2);
            pp += __shfl_xor(pp, 4);             // all 8 lanes: full dot
            float logit = pp + p.fc4_b[my_row];  // broadcast within group
            if (j == 0) p.out[my_row] = logit;
            // online (m, sumexp); every row counted 8x grid-wide (-> -ln8 later)
            if (logit > m) { s = s * __expf(m - logit) + 1.f; m = logit; }
            else           { s += __expf(logit - m); }
        }
    }

    // ---- block reduce (m, s) -> partials ----
    __shared__ float sm[NTHR], ss[NTHR];
    sm[t] = m; ss[t] = s;
    __syncthreads();
    for (int off = NTHR / 2; off > 0; off >>= 1) {
        if (t < off) {
            float m2 = sm[t + off], s2 = ss[t + off];
            float M  = fmaxf(sm[t], m2);
            ss[t] = ss[t] * expf(sm[t] - M) + s2 * expf(m2 - M);
            sm[t] = M;
        }
        __syncthreads();
    }
    if (t == 0) { p.ws[2 * bid] = sm[0]; p.ws[2 * bid + 1] = ss[0]; }
}

// ---------------------------------------------------------------------------
// K_B: every block redundantly reduces the 1024 partials -> lse (minus ln 8),
// then subtracts over its float4 slice of out.
// ---------------------------------------------------------------------------
__global__ __launch_bounds__(256) void finalize_kernel(
    const float* __restrict__ partials, float* __restrict__ out)
{
    __shared__ float sm[256], ss[256];
    __shared__ float lse_sh;
    const int t = threadIdx.x;

    float fm = -INFINITY, fs = 0.f;
    for (int i = t; i < NBLK; i += 256) {
        float m2 = partials[2 * i], s2 = partials[2 * i + 1];
        float M  = fmaxf(fm, m2);
        fs = fs * expf(fm - M) + s2 * expf(m2 - M);   // fs=0 kills exp(-inf) NaN path
        fm = M;
    }
    sm[t] = fm; ss[t] = fs;
    __syncthreads();
    for (int off = 128; off > 0; off >>= 1) {
        if (t < off) {
            float m2 = sm[t + off], s2 = ss[t + off];
            float M  = fmaxf(sm[t], m2);
            ss[t] = ss[t] * expf(sm[t] - M) + s2 * expf(m2 - M);
            sm[t] = M;
        }
        __syncthreads();
    }
    if (t == 0) lse_sh = sm[0] + logf(ss[0]) - LN8;
    __syncthreads();
    const float lse = lse_sh;

    const int idx = blockIdx.x * 256 + t;
    if (idx < ROWS / 4) {
        float4* o4 = (float4*)out;
        float4 v = o4[idx];
        v.x -= lse; v.y -= lse; v.z -= lse; v.w -= lse;
        o4[idx] = v;
    }
}

extern "C" void kernel_launch(void* const* d_in, const int* in_sizes, int n_in,
                              void* d_out, int out_size, void* d_ws, size_t ws_size,
                              hipStream_t stream) {
    Params pr;
    pr.x       = (const int*)  d_in[0];
    pr.hidden  = (const float*)d_in[1];
    pr.pos     = (const int*)  d_in[2];
    pr.loc_emb = (const float*)d_in[3];
    pr.arr_emb = (const float*)d_in[4];
    pr.dur_emb = (const float*)d_in[5];
    pr.pos_emb = (const float*)d_in[6];
    pr.f1rW1 = (const float*)d_in[7];
    pr.f1rb1 = (const float*)d_in[8];
    pr.f1rW2 = (const float*)d_in[9];
    pr.f1rb2 = (const float*)d_in[10];
    pr.f1W   = (const float*)d_in[11];
    pr.f1b   = (const float*)d_in[12];
    pr.f2rW1 = (const float*)d_in[13];
    pr.f2rb1 = (const float*)d_in[14];
    pr.f2rW2 = (const float*)d_in[15];
    pr.f2rb2 = (const float*)d_in[16];
    pr.f2W   = (const float*)d_in[17];
    pr.f2b   = (const float*)d_in[18];
    pr.f3rW1 = (const float*)d_in[19];
    pr.f3rb1 = (const float*)d_in[20];
    pr.f3rW2 = (const float*)d_in[21];
    pr.f3rb2 = (const float*)d_in[22];
    pr.f3W   = (const float*)d_in[23];
    pr.f3b   = (const float*)d_in[24];
    pr.ln_g  = (const float*)d_in[25];
    pr.ln_b  = (const float*)d_in[26];
    pr.ode_W = (const float*)d_in[27];
    pr.ode_b = (const float*)d_in[28];
    pr.oW1   = (const float*)d_in[29];
    pr.ob1   = (const float*)d_in[30];
    pr.oW2   = (const float*)d_in[31];
    pr.ob2   = (const float*)d_in[32];
    pr.fc4_W = (const float*)d_in[33];
    pr.fc4_b = (const float*)d_in[34];
    pr.fc5_W = (const float*)d_in[35];
    pr.fc5_b = (const float*)d_in[36];
    pr.fc6_W = (const float*)d_in[37];
    pr.fc6_b = (const float*)d_in[38];
    pr.gWih  = (const float*)d_in[39];
    pr.gbih  = (const float*)d_in[40];
    pr.gWhh  = (const float*)d_in[41];
    pr.gbhh  = (const float*)d_in[42];
    pr.out = (float*)d_out;
    pr.ws  = (float*)d_ws;

    bigkernel<<<NBLK, NTHR, 0, stream>>>(pr);
    finalize_kernel<<<NBLK_B, 256, 0, stream>>>((const float*)d_ws, (float*)d_out);
}

// Round 4
// 52.720 us; speedup vs baseline: 1.3939x; 1.3939x over previous
//
#include <hip/hip_runtime.h>
#include <math.h>

#define ROWS 1000000
#define NBLK_A 2048
#define NTHR 256
#define TOTAL (NBLK_A * NTHR)        // 524288 threads; each owns rows gid, gid+TOTAL
#define NBLK_B 977                   // ceil(250000 float4 / 256)

struct Params {
    const int*   x; const float* hidden; const int* pos;
    const float* loc_emb; const float* arr_emb; const float* dur_emb; const float* pos_emb;
    const float* f1rW1; const float* f1rb1; const float* f1rW2; const float* f1rb2;
    const float* f1W;   const float* f1b;
    const float* f2rW1; const float* f2rb1; const float* f2rW2; const float* f2rb2;
    const float* f2W;   const float* f2b;
    const float* f3rW1; const float* f3rb1; const float* f3rW2; const float* f3rb2;
    const float* f3W;   const float* f3b;
    const float* ln_g;  const float* ln_b;
    const float* ode_W; const float* ode_b;
    const float* oW1;   const float* ob1; const float* oW2; const float* ob2;
    const float* fc4_W; const float* fc4_b;
    const float* fc5_W; const float* fc5_b;
    const float* fc6_W; const float* fc6_b;
    const float* gWih;  const float* gbih; const float* gWhh; const float* gbhh;
    float* out; float* ws;
};

// ---------------------------------------------------------------------------
// K_A: prefetch row0 -> redundant front (wave 0) -> row0 from regs, row1
// streamed (8 loads in flight). Unnormalized logits to out, (m,s) partials
// to ws, small outputs from block 0.
// ---------------------------------------------------------------------------
__global__ __launch_bounds__(NTHR) void bigkernel(Params p)
{
    const int t   = threadIdx.x;
    const int bid = blockIdx.x;
    const int gid = bid * NTHR + t;        // row 0 index; always < TOTAL <= ROWS
    const float4* W4 = (const float4*)p.fc4_W;

    // ---- phase 0: issue row-0 loads immediately (independent of front) ----
    float4 a0[8];
    #pragma unroll
    for (int j = 0; j < 8; ++j) a0[j] = W4[(size_t)gid * 8 + j];
    float b0 = p.fc4_b[gid];

    // ---- front-end, wave 0 only (verified in rounds 1/3) ----
    __shared__ float e[3][16], tr[3][16], h1[3][16];
    __shared__ float praw[15], pnorm[15];
    __shared__ float ode0[32], odt[32], hvec[32], hnew[32], pe[32];
    __shared__ float gi[96], gh[96];
    __shared__ float a5[24], a6[24];
    __shared__ float red[4];

    if (t < 48) {
        int c = t >> 4, j = t & 15;
        const float* emb = (c == 0) ? (p.loc_emb + (size_t)p.x[0] * 16)
                         : (c == 1) ? (p.arr_emb + (size_t)p.x[1] * 16)
                                    : (p.dur_emb + (size_t)p.x[2] * 16);
        e[c][j] = emb[j];
    }
    if (t < 32) pe[t] = p.pos_emb[p.pos[0] * 32 + t];
    __syncthreads();

    for (int i = 0; i < 2; ++i) {
        if (t < 48) { int c = t >> 4, j = t & 15; tr[c][j] = fmaxf(e[c][j], 0.f); }
        __syncthreads();
        if (t < 48) {
            int c = t >> 4, j = t & 15;
            const float* W1 = ((c == 0) ? p.f1rW1 : (c == 1) ? p.f2rW1 : p.f3rW1) + i * 256 + j * 16;
            const float* b1 = ((c == 0) ? p.f1rb1 : (c == 1) ? p.f2rb1 : p.f3rb1) + i * 16;
            float a = b1[j];
            #pragma unroll
            for (int k = 0; k < 16; ++k) a += W1[k] * tr[c][k];
            h1[c][j] = fmaxf(a, 0.f);
        }
        __syncthreads();
        if (t < 48) {
            int c = t >> 4, j = t & 15;
            const float* W2 = ((c == 0) ? p.f1rW2 : (c == 1) ? p.f2rW2 : p.f3rW2) + i * 256 + j * 16;
            const float* b2 = ((c == 0) ? p.f1rb2 : (c == 1) ? p.f2rb2 : p.f3rb2) + i * 16;
            float a = b2[j];
            #pragma unroll
            for (int k = 0; k < 16; ++k) a += W2[k] * h1[c][k];
            e[c][j] += 0.3f * a;
        }
        __syncthreads();
    }

    if (t < 15) {
        int c = t / 5, q = t % 5;
        const float* W = ((c == 0) ? p.f1W : (c == 1) ? p.f2W : p.f3W) + q * 16;
        const float* b = ((c == 0) ? p.f1b : (c == 1) ? p.f2b : p.f3b);
        float a = b[q];
        #pragma unroll
        for (int k = 0; k < 16; ++k) a += W[k] * e[c][k];
        praw[t] = a;
    }
    __syncthreads();

    if (t == 0) {
        float mu = 0.f;
        for (int k = 0; k < 15; ++k) mu += praw[k];
        mu *= (1.f / 15.f);
        float var = 0.f;
        for (int k = 0; k < 15; ++k) { float d = praw[k] - mu; var += d * d; }
        var *= (1.f / 15.f);
        red[0] = mu;
        red[1] = rsqrtf(var + 1e-5f);
    }
    __syncthreads();
    if (t < 15) pnorm[t] = (praw[t] - red[0]) * red[1] * p.ln_g[t] + p.ln_b[t];
    if (t < 32) {
        float a = p.ode_b[t];
        const float* W = p.ode_W + t * 5;
        #pragma unroll
        for (int k = 0; k < 5; ++k) a += W[k] * praw[10 + k];
        ode0[t] = a;
    }
    __syncthreads();
    if (t < 32) {
        float a = p.ob1[t];
        const float* W = p.oW1 + t * 32;
        #pragma unroll
        for (int k = 0; k < 32; ++k) a += W[k] * fmaxf(ode0[k], 0.f);
        odt[t] = fmaxf(a, 0.f);
    }
    __syncthreads();
    if (t < 32) {
        float a = p.ob2[t];
        const float* W = p.oW2 + t * 32;
        #pragma unroll
        for (int k = 0; k < 32; ++k) a += W[k] * odt[k];
        hvec[t] = p.hidden[t] + ode0[t] + 0.3f * a;
    }
    __syncthreads();
    if (t < 64) {
        for (int q = t; q < 96; q += 64) {
            float a = p.gbih[q];
            const float* W = p.gWih + q * 15;
            #pragma unroll
            for (int k = 0; k < 15; ++k) a += W[k] * pnorm[k];
            gi[q] = a;
            float c2 = p.gbhh[q];
            const float* V = p.gWhh + q * 32;
            #pragma unroll
            for (int k = 0; k < 32; ++k) c2 += V[k] * hvec[k];
            gh[q] = c2;
        }
    }
    __syncthreads();
    if (t < 32) {
        float r = 1.f / (1.f + expf(-(gi[t] + gh[t])));
        float z = 1.f / (1.f + expf(-(gi[32 + t] + gh[32 + t])));
        float n = tanhf(gi[64 + t] + r * gh[64 + t]);
        float hn = (1.f - z) * n + z * hvec[t];
        hnew[t] = hn;
        if (bid == 0) p.out[ROWS + 48 + t] = hn;
    }
    __syncthreads();
    if (t < 24) {
        float a = p.fc5_b[t];
        const float* W = p.fc5_W + t * 32;
        #pragma unroll
        for (int k = 0; k < 32; ++k) a += W[k] * (hnew[k] + pe[k]);
        a5[t] = a;
        float b = p.fc6_b[t];
        const float* V = p.fc6_W + t * 32;
        #pragma unroll
        for (int k = 0; k < 32; ++k) b += V[k] * hnew[k];
        a6[t] = b;
    }
    __syncthreads();
    if (t == 0) {
        float m = -INFINITY;
        for (int k = 0; k < 24; ++k) m = fmaxf(m, a5[k]);
        float s = 0.f;
        for (int k = 0; k < 24; ++k) s += expf(a5[k] - m);
        red[2] = m + logf(s);
        m = -INFINITY;
        for (int k = 0; k < 24; ++k) m = fmaxf(m, a6[k]);
        s = 0.f;
        for (int k = 0; k < 24; ++k) s += expf(a6[k] - m);
        red[3] = m + logf(s);
    }
    __syncthreads();
    if (bid == 0 && t < 24) {
        p.out[ROWS + t]      = a5[t] - red[2];
        p.out[ROWS + 24 + t] = a6[t] - red[3];
    }

    // ---- fc4 logits: row0 from held regs, row1 streamed ----
    float hr[32];
    #pragma unroll
    for (int k = 0; k < 32; ++k) hr[k] = hnew[k];

    const int r1 = gid + TOTAL;
    const bool has1 = (r1 < ROWS);

    // issue row1 loads before consuming row0 (keep 8 in flight)
    float4 a1[8];
    if (has1) {
        #pragma unroll
        for (int j = 0; j < 8; ++j) a1[j] = W4[(size_t)r1 * 8 + j];
    }
    float b1v = has1 ? p.fc4_b[r1] : 0.f;

    float acc0 = b0;
    #pragma unroll
    for (int j = 0; j < 8; ++j)
        acc0 += a0[j].x * hr[4*j] + a0[j].y * hr[4*j+1]
              + a0[j].z * hr[4*j+2] + a0[j].w * hr[4*j+3];
    p.out[gid] = acc0;

    float m = acc0, s = 1.f;   // online (m, sumexp); row0 always valid

    if (has1) {
        float acc1 = b1v;
        #pragma unroll
        for (int j = 0; j < 8; ++j)
            acc1 += a1[j].x * hr[4*j] + a1[j].y * hr[4*j+1]
                  + a1[j].z * hr[4*j+2] + a1[j].w * hr[4*j+3];
        p.out[r1] = acc1;
        if (acc1 > m) { s = s * __expf(m - acc1) + 1.f; m = acc1; }
        else          { s += __expf(acc1 - m); }
    }

    // ---- block reduce (m, s) -> partials ----
    __shared__ float sm[NTHR], ss[NTHR];
    sm[t] = m; ss[t] = s;
    __syncthreads();
    for (int off = NTHR / 2; off > 0; off >>= 1) {
        if (t < off) {
            float m2 = sm[t + off], s2 = ss[t + off];
            float M  = fmaxf(sm[t], m2);
            ss[t] = ss[t] * expf(sm[t] - M) + s2 * expf(m2 - M);
            sm[t] = M;
        }
        __syncthreads();
    }
    if (t == 0) { p.ws[2 * bid] = sm[0]; p.ws[2 * bid + 1] = ss[0]; }
}

// ---------------------------------------------------------------------------
// K_B: every block redundantly reduces the 2048 partials -> lse, then
// subtracts over its float4 slice of out.
// ---------------------------------------------------------------------------
__global__ __launch_bounds__(256) void finalize_kernel(
    const float* __restrict__ partials, float* __restrict__ out)
{
    __shared__ float sm[256], ss[256];
    __shared__ float lse_sh;
    const int t = threadIdx.x;

    float fm = -INFINITY, fs = 0.f;
    for (int i = t; i < NBLK_A; i += 256) {
        float m2 = partials[2 * i], s2 = partials[2 * i + 1];
        float M  = fmaxf(fm, m2);
        fs = fs * expf(fm - M) + s2 * expf(m2 - M);
        fm = M;
    }
    sm[t] = fm; ss[t] = fs;
    __syncthreads();
    for (int off = 128; off > 0; off >>= 1) {
        if (t < off) {
            float m2 = sm[t + off], s2 = ss[t + off];
            float M  = fmaxf(sm[t], m2);
            ss[t] = ss[t] * expf(sm[t] - M) + s2 * expf(m2 - M);
            sm[t] = M;
        }
        __syncthreads();
    }
    if (t == 0) lse_sh = sm[0] + logf(ss[0]);
    __syncthreads();
    const float lse = lse_sh;

    const int idx = blockIdx.x * 256 + t;
    if (idx < ROWS / 4) {
        float4* o4 = (float4*)out;
        float4 v = o4[idx];
        v.x -= lse; v.y -= lse; v.z -= lse; v.w -= lse;
        o4[idx] = v;
    }
}

extern "C" void kernel_launch(void* const* d_in, const int* in_sizes, int n_in,
                              void* d_out, int out_size, void* d_ws, size_t ws_size,
                              hipStream_t stream) {
    Params pr;
    pr.x       = (const int*)  d_in[0];
    pr.hidden  = (const float*)d_in[1];
    pr.pos     = (const int*)  d_in[2];
    pr.loc_emb = (const float*)d_in[3];
    pr.arr_emb = (const float*)d_in[4];
    pr.dur_emb = (const float*)d_in[5];
    pr.pos_emb = (const float*)d_in[6];
    pr.f1rW1 = (const float*)d_in[7];
    pr.f1rb1 = (const float*)d_in[8];
    pr.f1rW2 = (const float*)d_in[9];
    pr.f1rb2 = (const float*)d_in[10];
    pr.f1W   = (const float*)d_in[11];
    pr.f1b   = (const float*)d_in[12];
    pr.f2rW1 = (const float*)d_in[13];
    pr.f2rb1 = (const float*)d_in[14];
    pr.f2rW2 = (const float*)d_in[15];
    pr.f2rb2 = (const float*)d_in[16];
    pr.f2W   = (const float*)d_in[17];
    pr.f2b   = (const float*)d_in[18];
    pr.f3rW1 = (const float*)d_in[19];
    pr.f3rb1 = (const float*)d_in[20];
    pr.f3rW2 = (const float*)d_in[21];
    pr.f3rb2 = (const float*)d_in[22];
    pr.f3W   = (const float*)d_in[23];
    pr.f3b   = (const float*)d_in[24];
    pr.ln_g  = (const float*)d_in[25];
    pr.ln_b  = (const float*)d_in[26];
    pr.ode_W = (const float*)d_in[27];
    pr.ode_b = (const float*)d_in[28];
    pr.oW1   = (const float*)d_in[29];
    pr.ob1   = (const float*)d_in[30];
    pr.oW2   = (const float*)d_in[31];
    pr.ob2   = (const float*)d_in[32];
    pr.fc4_W = (const float*)d_in[33];
    pr.fc4_b = (const float*)d_in[34];
    pr.fc5_W = (const float*)d_in[35];
    pr.fc5_b = (const float*)d_in[36];
    pr.fc6_W = (const float*)d_in[37];
    pr.fc6_b = (const float*)d_in[38];
    pr.gWih  = (const float*)d_in[39];
    pr.gbih  = (const float*)d_in[40];
    pr.gWhh  = (const float*)d_in[41];
    pr.gbhh  = (const float*)d_in[42];
    pr.out = (float*)d_out;
    pr.ws  = (float*)d_ws;

    bigkernel<<<NBLK_A, NTHR, 0, stream>>>(pr);
    finalize_kernel<<<NBLK_B, 256, 0, stream>>>((const float*)d_ws, (float*)d_out);
}

// Round 5
// 48.642 us; speedup vs baseline: 1.5108x; 1.0838x over previous
//
#include <hip/hip_runtime.h>
#include <math.h>

#define ROWS 1000000
#define NBLK_A 1024
#define NTHR 256
#define WAVES 4
#define GW (NBLK_A * WAVES)          // 4096 waves; 64 rows per wave-batch
#define NITER 4                      // 4096*64*4 = 1,048,576 >= ROWS
#define NBLK_B 977                   // ceil(250000 float4 / 256)
#define LN8 2.0794415416798357f

struct Params {
    const int*   x; const float* hidden; const int* pos;
    const float* loc_emb; const float* arr_emb; const float* dur_emb; const float* pos_emb;
    const float* f1rW1; const float* f1rb1; const float* f1rW2; const float* f1rb2;
    const float* f1W;   const float* f1b;
    const float* f2rW1; const float* f2rb1; const float* f2rW2; const float* f2rb2;
    const float* f2W;   const float* f2b;
    const float* f3rW1; const float* f3rb1; const float* f3rW2; const float* f3rb2;
    const float* f3W;   const float* f3b;
    const float* ln_g;  const float* ln_b;
    const float* ode_W; const float* ode_b;
    const float* oW1;   const float* ob1; const float* oW2; const float* ob2;
    const float* fc4_W; const float* fc4_b;
    const float* fc5_W; const float* fc5_b;
    const float* fc6_W; const float* fc6_b;
    const float* gWih;  const float* gbih; const float* gWhh; const float* gbhh;
    float* out; float* ws;
};

__global__ __launch_bounds__(NTHR) void bigkernel(Params p)
{
    const int t   = threadIdx.x;
    const int bid = blockIdx.x;
    const int l   = t & 63;
    const int wid = t >> 6;
    const int wg  = bid * WAVES + wid;   // global wave id
    const int j   = l & 7;               // chunk within row (cols 4j..4j+3)
    const int g   = l >> 3;              // row within wave's 8-row... (row within 64-f4 slab)
    const float4* W4 = (const float4*)p.fc4_W;

    // coalesced batch load: wave covers 64 consecutive float4 = 8 rows per chunk c
    // batch i, chunk c -> rows [rb, rb+8) with rb = ((i*GW+wg)*8+c)*8
#define LOADB(dst, it)                                                        \
    {   _Pragma("unroll")                                                     \
        for (int c = 0; c < 8; ++c) {                                         \
            size_t f4 = (size_t)(((it) * GW + wg) * 8 + c) * 64 + l;          \
            if (f4 >= (size_t)ROWS * 8) f4 = (size_t)ROWS * 8 - 1;            \
            dst[c] = W4[f4];                                                  \
        }                                                                     \
    }

    float4 bA[8], bB[8];
    LOADB(bA, 0)                         // in flight during the front

    // ---- front-end, wave 0 only (verified rounds 1/3/4) ----
    __shared__ float e[3][16], tr[3][16], h1[3][16];
    __shared__ float praw[15], pnorm[15];
    __shared__ float ode0[32], odt[32], hvec[32], hnew[32], pe[32];
    __shared__ float gi[96], gh[96];
    __shared__ float a5[24], a6[24];
    __shared__ float red[4];

    if (t < 48) {
        int c = t >> 4, jj = t & 15;
        const float* emb = (c == 0) ? (p.loc_emb + (size_t)p.x[0] * 16)
                         : (c == 1) ? (p.arr_emb + (size_t)p.x[1] * 16)
                                    : (p.dur_emb + (size_t)p.x[2] * 16);
        e[c][jj] = emb[jj];
    }
    if (t < 32) pe[t] = p.pos_emb[p.pos[0] * 32 + t];
    __syncthreads();

    for (int i = 0; i < 2; ++i) {
        if (t < 48) { int c = t >> 4, jj = t & 15; tr[c][jj] = fmaxf(e[c][jj], 0.f); }
        __syncthreads();
        if (t < 48) {
            int c = t >> 4, jj = t & 15;
            const float* W1 = ((c == 0) ? p.f1rW1 : (c == 1) ? p.f2rW1 : p.f3rW1) + i * 256 + jj * 16;
            const float* b1 = ((c == 0) ? p.f1rb1 : (c == 1) ? p.f2rb1 : p.f3rb1) + i * 16;
            float a = b1[jj];
            #pragma unroll
            for (int k = 0; k < 16; ++k) a += W1[k] * tr[c][k];
            h1[c][jj] = fmaxf(a, 0.f);
        }
        __syncthreads();
        if (t < 48) {
            int c = t >> 4, jj = t & 15;
            const float* W2 = ((c == 0) ? p.f1rW2 : (c == 1) ? p.f2rW2 : p.f3rW2) + i * 256 + jj * 16;
            const float* b2 = ((c == 0) ? p.f1rb2 : (c == 1) ? p.f2rb2 : p.f3rb2) + i * 16;
            float a = b2[jj];
            #pragma unroll
            for (int k = 0; k < 16; ++k) a += W2[k] * h1[c][k];
            e[c][jj] += 0.3f * a;
        }
        __syncthreads();
    }

    if (t < 15) {
        int c = t / 5, q = t % 5;
        const float* W = ((c == 0) ? p.f1W : (c == 1) ? p.f2W : p.f3W) + q * 16;
        const float* b = ((c == 0) ? p.f1b : (c == 1) ? p.f2b : p.f3b);
        float a = b[q];
        #pragma unroll
        for (int k = 0; k < 16; ++k) a += W[k] * e[c][k];
        praw[t] = a;
    }
    __syncthreads();

    if (t == 0) {
        float mu = 0.f;
        for (int k = 0; k < 15; ++k) mu += praw[k];
        mu *= (1.f / 15.f);
        float var = 0.f;
        for (int k = 0; k < 15; ++k) { float d = praw[k] - mu; var += d * d; }
        var *= (1.f / 15.f);
        red[0] = mu;
        red[1] = rsqrtf(var + 1e-5f);
    }
    __syncthreads();
    if (t < 15) pnorm[t] = (praw[t] - red[0]) * red[1] * p.ln_g[t] + p.ln_b[t];
    if (t < 32) {
        float a = p.ode_b[t];
        const float* W = p.ode_W + t * 5;
        #pragma unroll
        for (int k = 0; k < 5; ++k) a += W[k] * praw[10 + k];
        ode0[t] = a;
    }
    __syncthreads();
    if (t < 32) {
        float a = p.ob1[t];
        const float* W = p.oW1 + t * 32;
        #pragma unroll
        for (int k = 0; k < 32; ++k) a += W[k] * fmaxf(ode0[k], 0.f);
        odt[t] = fmaxf(a, 0.f);
    }
    __syncthreads();
    if (t < 32) {
        float a = p.ob2[t];
        const float* W = p.oW2 + t * 32;
        #pragma unroll
        for (int k = 0; k < 32; ++k) a += W[k] * odt[k];
        hvec[t] = p.hidden[t] + ode0[t] + 0.3f * a;
    }
    __syncthreads();
    if (t < 64) {
        for (int q = t; q < 96; q += 64) {
            float a = p.gbih[q];
            const float* W = p.gWih + q * 15;
            #pragma unroll
            for (int k = 0; k < 15; ++k) a += W[k] * pnorm[k];
            gi[q] = a;
            float c2 = p.gbhh[q];
            const float* V = p.gWhh + q * 32;
            #pragma unroll
            for (int k = 0; k < 32; ++k) c2 += V[k] * hvec[k];
            gh[q] = c2;
        }
    }
    __syncthreads();
    if (t < 32) {
        float r = 1.f / (1.f + expf(-(gi[t] + gh[t])));
        float z = 1.f / (1.f + expf(-(gi[32 + t] + gh[32 + t])));
        float n = tanhf(gi[64 + t] + r * gh[64 + t]);
        float hn = (1.f - z) * n + z * hvec[t];
        hnew[t] = hn;
        if (bid == 0) p.out[ROWS + 48 + t] = hn;
    }
    __syncthreads();
    if (t < 24) {
        float a = p.fc5_b[t];
        const float* W = p.fc5_W + t * 32;
        #pragma unroll
        for (int k = 0; k < 32; ++k) a += W[k] * (hnew[k] + pe[k]);
        a5[t] = a;
        float b = p.fc6_b[t];
        const float* V = p.fc6_W + t * 32;
        #pragma unroll
        for (int k = 0; k < 32; ++k) b += V[k] * hnew[k];
        a6[t] = b;
    }
    __syncthreads();
    if (t == 0) {
        float m = -INFINITY;
        for (int k = 0; k < 24; ++k) m = fmaxf(m, a5[k]);
        float s = 0.f;
        for (int k = 0; k < 24; ++k) s += expf(a5[k] - m);
        red[2] = m + logf(s);
        m = -INFINITY;
        for (int k = 0; k < 24; ++k) m = fmaxf(m, a6[k]);
        s = 0.f;
        for (int k = 0; k < 24; ++k) s += expf(a6[k] - m);
        red[3] = m + logf(s);
    }
    __syncthreads();
    if (bid == 0 && t < 24) {
        p.out[ROWS + t]      = a5[t] - red[2];
        p.out[ROWS + 24 + t] = a6[t] - red[3];
    }

    // ---- GEMV: coalesced loads, 8-lane shfl reduce, 8 groups in flight ----
    const float h0 = hnew[4 * j], h1v = hnew[4 * j + 1],
                h2 = hnew[4 * j + 2], h3 = hnew[4 * j + 3];
    float m = -INFINITY, s = 0.f;

#define PROCESS(src, it)                                                      \
    {   _Pragma("unroll")                                                     \
        for (int c = 0; c < 8; ++c) {                                         \
            float pp = src[c].x * h0 + src[c].y * h1v                         \
                     + src[c].z * h2 + src[c].w * h3;                         \
            pp += __shfl_xor(pp, 1);                                          \
            pp += __shfl_xor(pp, 2);                                          \
            pp += __shfl_xor(pp, 4);                                          \
            int row = (((it) * GW + wg) * 8 + c) * 8 + g;                     \
            if (row < ROWS) {                                                 \
                float logit = pp + p.fc4_b[row];                              \
                if (j == 0) p.out[row] = logit;                               \
                if (logit > m) { s = s * __expf(m - logit) + 1.f; m = logit; }\
                else           { s += __expf(logit - m); }                    \
            }                                                                 \
        }                                                                     \
    }

    LOADB(bB, 1)  PROCESS(bA, 0)
    LOADB(bA, 2)  PROCESS(bB, 1)
    LOADB(bB, 3)  PROCESS(bA, 2)
                  PROCESS(bB, 3)

    // ---- block reduce (m, s) -> partials (each logit counted 8x) ----
    __shared__ float sm[NTHR], ss[NTHR];
    sm[t] = m; ss[t] = s;
    __syncthreads();
    for (int off = NTHR / 2; off > 0; off >>= 1) {
        if (t < off) {
            float m2 = sm[t + off], s2 = ss[t + off];
            float M  = fmaxf(sm[t], m2);
            ss[t] = ss[t] * expf(sm[t] - M) + s2 * expf(m2 - M);
            sm[t] = M;
        }
        __syncthreads();
    }
    if (t == 0) { p.ws[2 * bid] = sm[0]; p.ws[2 * bid + 1] = ss[0]; }
}

// ---------------------------------------------------------------------------
// K_B: every block redundantly reduces the 1024 partials -> lse (8x counted
// -> minus ln8), then subtracts over its float4 slice of out.
// ---------------------------------------------------------------------------
__global__ __launch_bounds__(256) void finalize_kernel(
    const float* __restrict__ partials, float* __restrict__ out)
{
    __shared__ float sm[256], ss[256];
    __shared__ float lse_sh;
    const int t = threadIdx.x;

    float fm = -INFINITY, fs = 0.f;
    for (int i = t; i < NBLK_A; i += 256) {
        float m2 = partials[2 * i], s2 = partials[2 * i + 1];
        float M  = fmaxf(fm, m2);
        fs = fs * expf(fm - M) + s2 * expf(m2 - M);
        fm = M;
    }
    sm[t] = fm; ss[t] = fs;
    __syncthreads();
    for (int off = 128; off > 0; off >>= 1) {
        if (t < off) {
            float m2 = sm[t + off], s2 = ss[t + off];
            float M  = fmaxf(sm[t], m2);
            ss[t] = ss[t] * expf(sm[t] - M) + s2 * expf(m2 - M);
            sm[t] = M;
        }
        __syncthreads();
    }
    if (t == 0) lse_sh = sm[0] + logf(ss[0]) - LN8;
    __syncthreads();
    const float lse = lse_sh;

    const int idx = blockIdx.x * 256 + t;
    if (idx < ROWS / 4) {
        float4* o4 = (float4*)out;
        float4 v = o4[idx];
        v.x -= lse; v.y -= lse; v.z -= lse; v.w -= lse;
        o4[idx] = v;
    }
}

extern "C" void kernel_launch(void* const* d_in, const int* in_sizes, int n_in,
                              void* d_out, int out_size, void* d_ws, size_t ws_size,
                              hipStream_t stream) {
    Params pr;
    pr.x       = (const int*)  d_in[0];
    pr.hidden  = (const float*)d_in[1];
    pr.pos     = (const int*)  d_in[2];
    pr.loc_emb = (const float*)d_in[3];
    pr.arr_emb = (const float*)d_in[4];
    pr.dur_emb = (const float*)d_in[5];
    pr.pos_emb = (const float*)d_in[6];
    pr.f1rW1 = (const float*)d_in[7];
    pr.f1rb1 = (const float*)d_in[8];
    pr.f1rW2 = (const float*)d_in[9];
    pr.f1rb2 = (const float*)d_in[10];
    pr.f1W   = (const float*)d_in[11];
    pr.f1b   = (const float*)d_in[12];
    pr.f2rW1 = (const float*)d_in[13];
    pr.f2rb1 = (const float*)d_in[14];
    pr.f2rW2 = (const float*)d_in[15];
    pr.f2rb2 = (const float*)d_in[16];
    pr.f2W   = (const float*)d_in[17];
    pr.f2b   = (const float*)d_in[18];
    pr.f3rW1 = (const float*)d_in[19];
    pr.f3rb1 = (const float*)d_in[20];
    pr.f3rW2 = (const float*)d_in[21];
    pr.f3rb2 = (const float*)d_in[22];
    pr.f3W   = (const float*)d_in[23];
    pr.f3b   = (const float*)d_in[24];
    pr.ln_g  = (const float*)d_in[25];
    pr.ln_b  = (const float*)d_in[26];
    pr.ode_W = (const float*)d_in[27];
    pr.ode_b = (const float*)d_in[28];
    pr.oW1   = (const float*)d_in[29];
    pr.ob1   = (const float*)d_in[30];
    pr.oW2   = (const float*)d_in[31];
    pr.ob2   = (const float*)d_in[32];
    pr.fc4_W = (const float*)d_in[33];
    pr.fc4_b = (const float*)d_in[34];
    pr.fc5_W = (const float*)d_in[35];
    pr.fc5_b = (const float*)d_in[36];
    pr.fc6_W = (const float*)d_in[37];
    pr.fc6_b = (const float*)d_in[38];
    pr.gWih  = (const float*)d_in[39];
    pr.gbih  = (const float*)d_in[40];
    pr.gWhh  = (const float*)d_in[41];
    pr.gbhh  = (const float*)d_in[42];
    pr.out = (float*)d_out;
    pr.ws  = (float*)d_ws;

    bigkernel<<<NBLK_A, NTHR, 0, stream>>>(pr);
    finalize_kernel<<<NBLK_B, 256, 0, stream>>>((const float*)d_ws, (float*)d_out);
}

// Round 6
// 45.146 us; speedup vs baseline: 1.6278x; 1.0774x over previous
//
#include <hip/hip_runtime.h>
#include <math.h>
#include <float.h>

#define ROWS 1000000
#define NTHR 256
#define NBLK_L 3907                  // ceil(1e6 / 256)  -> one row per thread
#define NBLK_B 977                   // ceil(250000 float4 / 256)
#define NEG_BIG (-3.0e38f)

// ---------------------------------------------------------------------------
// K0: front (1 block x 128) — byte-identical logic to the round-1 PASSING code.
// Writes h_new to ws[0:32] and the small outputs.
// ---------------------------------------------------------------------------
__global__ __launch_bounds__(128) void front_kernel(
    const int* __restrict__ x, const float* __restrict__ hidden, const int* __restrict__ pos,
    const float* __restrict__ loc_emb, const float* __restrict__ arr_emb,
    const float* __restrict__ dur_emb, const float* __restrict__ pos_emb,
    const float* __restrict__ f1rW1, const float* __restrict__ f1rb1,
    const float* __restrict__ f1rW2, const float* __restrict__ f1rb2,
    const float* __restrict__ f1W,   const float* __restrict__ f1b,
    const float* __restrict__ f2rW1, const float* __restrict__ f2rb1,
    const float* __restrict__ f2rW2, const float* __restrict__ f2rb2,
    const float* __restrict__ f2W,   const float* __restrict__ f2b,
    const float* __restrict__ f3rW1, const float* __restrict__ f3rb1,
    const float* __restrict__ f3rW2, const float* __restrict__ f3rb2,
    const float* __restrict__ f3W,   const float* __restrict__ f3b,
    const float* __restrict__ ln_g,  const float* __restrict__ ln_b,
    const float* __restrict__ ode_W, const float* __restrict__ ode_b,
    const float* __restrict__ oW1,   const float* __restrict__ ob1,
    const float* __restrict__ oW2,   const float* __restrict__ ob2,
    const float* __restrict__ fc5_W, const float* __restrict__ fc5_b,
    const float* __restrict__ fc6_W, const float* __restrict__ fc6_b,
    const float* __restrict__ gWih,  const float* __restrict__ gbih,
    const float* __restrict__ gWhh,  const float* __restrict__ gbhh,
    float* __restrict__ out, float* __restrict__ ws)
{
    __shared__ float e[3][16], tr[3][16], h1[3][16];
    __shared__ float praw[15], pnorm[15];
    __shared__ float ode0[32], odt[32], hvec[32], hnew[32], pe[32];
    __shared__ float gi[96], gh[96];
    __shared__ float a5[24], a6[24];
    __shared__ float red[4];

    const int t = threadIdx.x;

    if (t < 48) {
        int c = t >> 4, j = t & 15;
        const float* emb = (c == 0) ? (loc_emb + (size_t)x[0] * 16)
                         : (c == 1) ? (arr_emb + (size_t)x[1] * 16)
                                    : (dur_emb + (size_t)x[2] * 16);
        e[c][j] = emb[j];
    }
    if (t < 32) pe[t] = pos_emb[pos[0] * 32 + t];
    __syncthreads();

    for (int i = 0; i < 2; ++i) {
        if (t < 48) { int c = t >> 4, j = t & 15; tr[c][j] = fmaxf(e[c][j], 0.f); }
        __syncthreads();
        if (t < 48) {
            int c = t >> 4, j = t & 15;
            const float* W1 = ((c == 0) ? f1rW1 : (c == 1) ? f2rW1 : f3rW1) + i * 256 + j * 16;
            const float* b1 = ((c == 0) ? f1rb1 : (c == 1) ? f2rb1 : f3rb1) + i * 16;
            float a = b1[j];
            #pragma unroll
            for (int k = 0; k < 16; ++k) a += W1[k] * tr[c][k];
            h1[c][j] = fmaxf(a, 0.f);
        }
        __syncthreads();
        if (t < 48) {
            int c = t >> 4, j = t & 15;
            const float* W2 = ((c == 0) ? f1rW2 : (c == 1) ? f2rW2 : f3rW2) + i * 256 + j * 16;
            const float* b2 = ((c == 0) ? f1rb2 : (c == 1) ? f2rb2 : f3rb2) + i * 16;
            float a = b2[j];
            #pragma unroll
            for (int k = 0; k < 16; ++k) a += W2[k] * h1[c][k];
            e[c][j] += 0.3f * a;
        }
        __syncthreads();
    }

    if (t < 15) {
        int c = t / 5, q = t % 5;
        const float* W = ((c == 0) ? f1W : (c == 1) ? f2W : f3W) + q * 16;
        const float* b = ((c == 0) ? f1b : (c == 1) ? f2b : f3b);
        float a = b[q];
        #pragma unroll
        for (int k = 0; k < 16; ++k) a += W[k] * e[c][k];
        praw[t] = a;
    }
    __syncthreads();

    if (t == 0) {
        float mu = 0.f;
        for (int k = 0; k < 15; ++k) mu += praw[k];
        mu *= (1.f / 15.f);
        float var = 0.f;
        for (int k = 0; k < 15; ++k) { float d = praw[k] - mu; var += d * d; }
        var *= (1.f / 15.f);
        red[0] = mu;
        red[1] = rsqrtf(var + 1e-5f);
    }
    __syncthreads();
    if (t < 15) pnorm[t] = (praw[t] - red[0]) * red[1] * ln_g[t] + ln_b[t];
    if (t < 32) {
        float a = ode_b[t];
        const float* W = ode_W + t * 5;
        #pragma unroll
        for (int k = 0; k < 5; ++k) a += W[k] * praw[10 + k];
        ode0[t] = a;
    }
    __syncthreads();
    if (t < 32) {
        float a = ob1[t];
        const float* W = oW1 + t * 32;
        #pragma unroll
        for (int k = 0; k < 32; ++k) a += W[k] * fmaxf(ode0[k], 0.f);
        odt[t] = fmaxf(a, 0.f);
    }
    __syncthreads();
    if (t < 32) {
        float a = ob2[t];
        const float* W = oW2 + t * 32;
        #pragma unroll
        for (int k = 0; k < 32; ++k) a += W[k] * odt[k];
        hvec[t] = hidden[t] + ode0[t] + 0.3f * a;
    }
    __syncthreads();
    if (t < 96) {
        float a = gbih[t];
        const float* W = gWih + t * 15;
        #pragma unroll
        for (int k = 0; k < 15; ++k) a += W[k] * pnorm[k];
        gi[t] = a;
        float c2 = gbhh[t];
        const float* V = gWhh + t * 32;
        #pragma unroll
        for (int k = 0; k < 32; ++k) c2 += V[k] * hvec[k];
        gh[t] = c2;
    }
    __syncthreads();
    if (t < 32) {
        float r = 1.f / (1.f + expf(-(gi[t] + gh[t])));
        float z = 1.f / (1.f + expf(-(gi[32 + t] + gh[32 + t])));
        float n = tanhf(gi[64 + t] + r * gh[64 + t]);
        float hn = (1.f - z) * n + z * hvec[t];
        hnew[t] = hn;
        ws[t] = hn;
        out[ROWS + 48 + t] = hn;
    }
    __syncthreads();
    if (t < 24) {
        float a = fc5_b[t];
        const float* W = fc5_W + t * 32;
        #pragma unroll
        for (int k = 0; k < 32; ++k) a += W[k] * (hnew[k] + pe[k]);
        a5[t] = a;
        float b = fc6_b[t];
        const float* V = fc6_W + t * 32;
        #pragma unroll
        for (int k = 0; k < 32; ++k) b += V[k] * hnew[k];
        a6[t] = b;
    }
    __syncthreads();
    if (t == 0) {
        float m = -INFINITY;
        for (int k = 0; k < 24; ++k) m = fmaxf(m, a5[k]);
        float s = 0.f;
        for (int k = 0; k < 24; ++k) s += expf(a5[k] - m);
        red[2] = m + logf(s);
        m = -INFINITY;
        for (int k = 0; k < 24; ++k) m = fmaxf(m, a6[k]);
        s = 0.f;
        for (int k = 0; k < 24; ++k) s += expf(a6[k] - m);
        red[3] = m + logf(s);
    }
    __syncthreads();
    if (t < 24) {
        out[ROWS + t]      = a5[t] - red[2];
        out[ROWS + 24 + t] = a6[t] - red[3];
    }
}

// ---------------------------------------------------------------------------
// K1: one row per thread. 8 independent float4 loads -> one wait -> 32 FMA ->
// coalesced store. No loop-carried state, minimal VGPR, occupancy-limited by
// registers only. Block (m,s) partial -> ws (as float2).
// ---------------------------------------------------------------------------
__global__ __launch_bounds__(NTHR) void logits_kernel(
    const float* __restrict__ W, const float* __restrict__ b,
    const float* __restrict__ ws_h, float* __restrict__ out,
    float2* __restrict__ partials)
{
    __shared__ float hs[32];
    if (threadIdx.x < 32) hs[threadIdx.x] = ws_h[threadIdx.x];
    __syncthreads();

    const int t = threadIdx.x;
    const int r = blockIdx.x * NTHR + t;

    float m = NEG_BIG, s = 0.f;
    if (r < ROWS) {
        const float4* W4 = (const float4*)W;
        float4 w[8];
        #pragma unroll
        for (int j = 0; j < 8; ++j) w[j] = W4[(size_t)r * 8 + j];
        float acc = b[r];
        #pragma unroll
        for (int j = 0; j < 8; ++j)
            acc += w[j].x * hs[4*j] + w[j].y * hs[4*j+1]
                 + w[j].z * hs[4*j+2] + w[j].w * hs[4*j+3];
        out[r] = acc;
        m = acc; s = 1.f;
    }

    __shared__ float sm[NTHR], ss[NTHR];
    sm[t] = m; ss[t] = s;
    __syncthreads();
    for (int off = NTHR / 2; off > 0; off >>= 1) {
        if (t < off) {
            float m2 = sm[t + off], s2 = ss[t + off];
            float M  = fmaxf(sm[t], m2);
            ss[t] = ss[t] * __expf(sm[t] - M) + s2 * __expf(m2 - M);
            sm[t] = M;
        }
        __syncthreads();
    }
    if (t == 0) partials[blockIdx.x] = make_float2(sm[0], ss[0]);
}

// ---------------------------------------------------------------------------
// K2: every block redundantly reduces the 3907 partials -> lse, then
// subtracts over its float4 slice of out.
// ---------------------------------------------------------------------------
__global__ __launch_bounds__(256) void finalize_kernel(
    const float2* __restrict__ partials, float* __restrict__ out)
{
    __shared__ float sm[256], ss[256];
    __shared__ float lse_sh;
    const int t = threadIdx.x;

    float fm = NEG_BIG, fs = 0.f;
    for (int i = t; i < NBLK_L; i += 256) {
        float2 p2 = partials[i];
        float M = fmaxf(fm, p2.x);
        fs = fs * __expf(fm - M) + p2.y * __expf(p2.x - M);
        fm = M;
    }
    sm[t] = fm; ss[t] = fs;
    __syncthreads();
    for (int off = 128; off > 0; off >>= 1) {
        if (t < off) {
            float m2 = sm[t + off], s2 = ss[t + off];
            float M  = fmaxf(sm[t], m2);
            ss[t] = ss[t] * __expf(sm[t] - M) + s2 * __expf(m2 - M);
            sm[t] = M;
        }
        __syncthreads();
    }
    if (t == 0) lse_sh = sm[0] + logf(ss[0]);
    __syncthreads();
    const float lse = lse_sh;

    const int idx = blockIdx.x * 256 + t;
    if (idx < ROWS / 4) {
        float4* o4 = (float4*)out;
        float4 v = o4[idx];
        v.x -= lse; v.y -= lse; v.z -= lse; v.w -= lse;
        o4[idx] = v;
    }
}

extern "C" void kernel_launch(void* const* d_in, const int* in_sizes, int n_in,
                              void* d_out, int out_size, void* d_ws, size_t ws_size,
                              hipStream_t stream) {
    const int*   x       = (const int*)  d_in[0];
    const float* hidden  = (const float*)d_in[1];
    const int*   pos     = (const int*)  d_in[2];
    const float* loc_emb = (const float*)d_in[3];
    const float* arr_emb = (const float*)d_in[4];
    const float* dur_emb = (const float*)d_in[5];
    const float* pos_emb = (const float*)d_in[6];
    const float* f1rW1 = (const float*)d_in[7];
    const float* f1rb1 = (const float*)d_in[8];
    const float* f1rW2 = (const float*)d_in[9];
    const float* f1rb2 = (const float*)d_in[10];
    const float* f1W   = (const float*)d_in[11];
    const float* f1b   = (const float*)d_in[12];
    const float* f2rW1 = (const float*)d_in[13];
    const float* f2rb1 = (const float*)d_in[14];
    const float* f2rW2 = (const float*)d_in[15];
    const float* f2rb2 = (const float*)d_in[16];
    const float* f2W   = (const float*)d_in[17];
    const float* f2b   = (const float*)d_in[18];
    const float* f3rW1 = (const float*)d_in[19];
    const float* f3rb1 = (const float*)d_in[20];
    const float* f3rW2 = (const float*)d_in[21];
    const float* f3rb2 = (const float*)d_in[22];
    const float* f3W   = (const float*)d_in[23];
    const float* f3b   = (const float*)d_in[24];
    const float* ln_g  = (const float*)d_in[25];
    const float* ln_b  = (const float*)d_in[26];
    const float* ode_W = (const float*)d_in[27];
    const float* ode_b = (const float*)d_in[28];
    const float* oW1   = (const float*)d_in[29];
    const float* ob1   = (const float*)d_in[30];
    const float* oW2   = (const float*)d_in[31];
    const float* ob2   = (const float*)d_in[32];
    const float* fc4_W = (const float*)d_in[33];
    const float* fc4_b = (const float*)d_in[34];
    const float* fc5_W = (const float*)d_in[35];
    const float* fc5_b = (const float*)d_in[36];
    const float* fc6_W = (const float*)d_in[37];
    const float* fc6_b = (const float*)d_in[38];
    const float* gWih  = (const float*)d_in[39];
    const float* gbih  = (const float*)d_in[40];
    const float* gWhh  = (const float*)d_in[41];
    const float* gbhh  = (const float*)d_in[42];

    float* out = (float*)d_out;
    float* wsf = (float*)d_ws;
    // ws layout: [0:32) h_new ; [64 : 64+2*NBLK_L) partials (float2-aligned)
    float*  ws_h        = wsf;
    float2* ws_partials = (float2*)(wsf + 64);

    front_kernel<<<1, 128, 0, stream>>>(
        x, hidden, pos, loc_emb, arr_emb, dur_emb, pos_emb,
        f1rW1, f1rb1, f1rW2, f1rb2, f1W, f1b,
        f2rW1, f2rb1, f2rW2, f2rb2, f2W, f2b,
        f3rW1, f3rb1, f3rW2, f3rb2, f3W, f3b,
        ln_g, ln_b, ode_W, ode_b, oW1, ob1, oW2, ob2,
        fc5_W, fc5_b, fc6_W, fc6_b, gWih, gbih, gWhh, gbhh,
        out, ws_h);

    logits_kernel<<<NBLK_L, NTHR, 0, stream>>>(
        fc4_W, fc4_b, ws_h, out, ws_partials);

    finalize_kernel<<<NBLK_B, 256, 0, stream>>>(ws_partials, out);
}